// Round 3
// baseline (415.996 us; speedup 1.0000x reference)
//
#include <hip/hip_runtime.h>
#include <stdint.h>

#define N_NODES   50000
#define K_DIM     128
#define OUT_DIM   32
#define N_EDGES   1600000
#define NPB       64                         // nodes per bucket (pow2)
#define NBKT      782                        // ceil(50000/64)
#define FITEMS    16                         // edges per thread in hist/fill
#define FBLOCKS   ((N_EDGES + 256*FITEMS - 1) / (256*FITEMS))   // 391

// -------- h = x @ W : [50000,128] x [128,32] -> [50000,32] --------
__global__ __launch_bounds__(256) void gemm_kernel(const float* __restrict__ x,
                                                   const float* __restrict__ w,
                                                   float* __restrict__ h) {
    __shared__ float wlds[K_DIM * OUT_DIM];
    const int t = threadIdx.x;
    #pragma unroll
    for (int i = 0; i < (K_DIM * OUT_DIM) / 256; ++i)
        wlds[i * 256 + t] = w[i * 256 + t];
    __syncthreads();

    const int row = blockIdx.x * 8 + (t >> 5);
    const int col = t & 31;
    if (row >= N_NODES) return;

    const float4* x4 = reinterpret_cast<const float4*>(x + (size_t)row * K_DIM);
    float acc = 0.f;
    #pragma unroll
    for (int k4 = 0; k4 < K_DIM / 4; ++k4) {
        float4 xv = x4[k4];
        const int k = k4 * 4;
        acc += xv.x * wlds[(k + 0) * OUT_DIM + col];
        acc += xv.y * wlds[(k + 1) * OUT_DIM + col];
        acc += xv.z * wlds[(k + 2) * OUT_DIM + col];
        acc += xv.w * wlds[(k + 3) * OUT_DIM + col];
    }
    h[(size_t)row * OUT_DIM + col] = acc;
}

// -------- bucket histogram (LDS-aggregated) --------
__global__ __launch_bounds__(256) void bucket_hist(const int* __restrict__ edst,
                                                   int* __restrict__ counts) {
    __shared__ int cnt[NBKT];
    const int t = threadIdx.x;
    for (int i = t; i < NBKT; i += 256) cnt[i] = 0;
    __syncthreads();
    const int base = blockIdx.x * 256 * FITEMS;
    #pragma unroll
    for (int k = 0; k < FITEMS; ++k) {
        const int e = base + k * 256 + t;
        if (e < N_EDGES) atomicAdd(&cnt[edst[e] >> 6], 1);
    }
    __syncthreads();
    for (int i = t; i < NBKT; i += 256) {
        const int c = cnt[i];
        if (c) atomicAdd(&counts[i], c);
    }
}

// -------- parallel exclusive scan of 782 bucket counts (one block) --------
__global__ __launch_bounds__(1024) void bucket_scan(const int* __restrict__ counts,
                                                    int* __restrict__ bases,
                                                    int* __restrict__ cursor) {
    __shared__ int s[1024];
    const int t = threadIdx.x;
    const int v = (t < NBKT) ? counts[t] : 0;
    s[t] = v;
    __syncthreads();
    #pragma unroll
    for (int d = 1; d < 1024; d <<= 1) {
        int xv = 0;
        if (t >= d) xv = s[t - d];
        __syncthreads();
        if (t >= d) s[t] += xv;
        __syncthreads();
    }
    if (t < NBKT) {
        const int excl = s[t] - v;
        bases[t]  = excl;
        cursor[t] = excl;
    }
}

// -------- fill: bucket-grouped (w,dst,src) pairs, register-held items --------
__global__ __launch_bounds__(256) void bucket_fill(const int*   __restrict__ esrc,
                                                   const int*   __restrict__ edst,
                                                   const float* __restrict__ ew,
                                                   int*         __restrict__ cursor,
                                                   uint64_t*    __restrict__ pairs) {
    __shared__ int cnt[NBKT];
    __shared__ int wbase[NBKT];
    const int t = threadIdx.x;
    for (int i = t; i < NBKT; i += 256) cnt[i] = 0;
    __syncthreads();

    uint32_t lo[FITEMS], hi[FITEMS];
    const int base = blockIdx.x * 256 * FITEMS;
    #pragma unroll
    for (int k = 0; k < FITEMS; ++k) {
        const int e = base + k * 256 + t;
        if (e < N_EDGES) {
            const uint32_t s = (uint32_t)esrc[e];
            const uint32_t d = (uint32_t)edst[e];
            lo[k] = (d << 16) | s;            // dst:16 | src:16 (both < 65536)
            hi[k] = __float_as_uint(ew[e]);
            atomicAdd(&cnt[d >> 6], 1);
        } else {
            lo[k] = 0xffffffffu;              // invalid marker (never a real pair)
        }
    }
    __syncthreads();
    for (int i = t; i < NBKT; i += 256) {
        const int c = cnt[i];
        if (c) wbase[i] = atomicAdd(&cursor[i], c);
    }
    __syncthreads();
    for (int i = t; i < NBKT; i += 256) cnt[i] = 0;   // reuse as running rank
    __syncthreads();
    #pragma unroll
    for (int k = 0; k < FITEMS; ++k) {
        if (lo[k] != 0xffffffffu) {
            const int b = (int)(lo[k] >> 22);          // dst >> 6
            const int r = atomicAdd(&cnt[b], 1);
            pairs[(size_t)wbase[b] + r] = ((uint64_t)hi[k] << 32) | lo[k];
        }
    }
}

// -------- pull: block per bucket, LDS accumulator, no global float atomics ----
__global__ __launch_bounds__(256) void bucket_pull(const int*      __restrict__ bases,
                                                   const int*      __restrict__ counts,
                                                   const uint64_t* __restrict__ pairs,
                                                   const float*    __restrict__ h,
                                                   float*          __restrict__ out) {
    __shared__ float acc[NPB * OUT_DIM];     // 8 KB
    const int t = threadIdx.x;
    #pragma unroll
    for (int i = 0; i < (NPB * OUT_DIM) / 256; ++i) acc[i * 256 + t] = 0.f;
    __syncthreads();

    const int b   = blockIdx.x;
    const int beg = bases[b];
    const int end = beg + counts[b];
    const int g   = t >> 5;                  // 8 groups of 32 lanes
    const int col = t & 31;

    int j = beg + g;
    for (; j + 8 < end; j += 16) {           // 2 edges in flight per group
        const uint64_t p0 = pairs[j];
        const uint64_t p1 = pairs[j + 8];
        const uint32_t lo0 = (uint32_t)p0, lo1 = (uint32_t)p1;
        const float w0 = __uint_as_float((uint32_t)(p0 >> 32));
        const float w1 = __uint_as_float((uint32_t)(p1 >> 32));
        const float v0 = w0 * h[(size_t)(lo0 & 0xffffu) * OUT_DIM + col];
        const float v1 = w1 * h[(size_t)(lo1 & 0xffffu) * OUT_DIM + col];
        unsafeAtomicAdd(&acc[(((lo0 >> 16) & (NPB - 1)) << 5) | col], v0);
        unsafeAtomicAdd(&acc[(((lo1 >> 16) & (NPB - 1)) << 5) | col], v1);
    }
    if (j < end) {
        const uint64_t p0 = pairs[j];
        const uint32_t lo0 = (uint32_t)p0;
        const float w0 = __uint_as_float((uint32_t)(p0 >> 32));
        const float v0 = w0 * h[(size_t)(lo0 & 0xffffu) * OUT_DIM + col];
        unsafeAtomicAdd(&acc[(((lo0 >> 16) & (NPB - 1)) << 5) | col], v0);
    }
    __syncthreads();

    // coalesced float4 write-out (covers all rows -> no d_out memset needed)
    const long long g4base = (long long)b * (NPB * OUT_DIM / 4);
    float4* out4 = reinterpret_cast<float4*>(out);
    const float4* a4 = reinterpret_cast<const float4*>(acc);
    #pragma unroll
    for (int k = 0; k < (NPB * OUT_DIM / 4) / 256; ++k) {   // 2 iters
        const long long idx4 = g4base + k * 256 + t;
        if (idx4 < (long long)N_NODES * OUT_DIM / 4)
            out4[idx4] = a4[k * 256 + t];
    }
}

// -------- fallback scatter (R1 path) if workspace too small --------
__global__ __launch_bounds__(256) void scatter_kernel(const int*   __restrict__ esrc,
                                                      const int*   __restrict__ edst,
                                                      const float* __restrict__ ew,
                                                      const float* __restrict__ h,
                                                      float*       out) {
    const long long gid = (long long)blockIdx.x * blockDim.x + threadIdx.x;
    const int e   = (int)(gid >> 5);
    const int col = (int)(gid & 31);
    if (e >= N_EDGES) return;
    atomicAdd(out + (size_t)edst[e] * OUT_DIM + col,
              ew[e] * h[(size_t)esrc[e] * OUT_DIM + col]);
}

extern "C" void kernel_launch(void* const* d_in, const int* in_sizes, int n_in,
                              void* d_out, int out_size, void* d_ws, size_t ws_size,
                              hipStream_t stream) {
    const float* x    = (const float*)d_in[0];
    const float* w    = (const float*)d_in[1];
    const int*   esrc = (const int*)d_in[2];
    const int*   edst = (const int*)d_in[3];
    const float* ew   = (const float*)d_in[4];
    float*       out  = (float*)d_out;

    const size_t PAIRS_B = (size_t)N_EDGES * 8;            // 12.8 MB
    const size_t H_B     = (size_t)N_NODES * OUT_DIM * 4;  //  6.4 MB
    const size_t CNT_B   = (size_t)NBKT * 4;               //  3128 B
    const size_t REQ     = PAIRS_B + H_B + 3 * CNT_B + 256;

    if (ws_size >= REQ) {
        uint64_t* pairs  = (uint64_t*)d_ws;
        float*    h      = (float*)((char*)d_ws + PAIRS_B);
        int*      counts = (int*)((char*)d_ws + PAIRS_B + H_B);
        int*      bases  = counts + NBKT;
        int*      cursor = bases + NBKT;

        gemm_kernel<<<(N_NODES + 7) / 8, 256, 0, stream>>>(x, w, h);

        hipMemsetAsync(counts, 0, CNT_B, stream);
        bucket_hist<<<FBLOCKS, 256, 0, stream>>>(edst, counts);
        bucket_scan<<<1, 1024, 0, stream>>>(counts, bases, cursor);
        bucket_fill<<<FBLOCKS, 256, 0, stream>>>(esrc, edst, ew, cursor, pairs);
        bucket_pull<<<NBKT, 256, 0, stream>>>(bases, counts, pairs, h, out);
    } else {
        float* h = (float*)d_ws;
        hipMemsetAsync(d_out, 0, (size_t)out_size * sizeof(float), stream);
        gemm_kernel<<<(N_NODES + 7) / 8, 256, 0, stream>>>(x, w, h);
        const long long total = (long long)N_EDGES * OUT_DIM;
        scatter_kernel<<<(int)((total + 255) / 256), 256, 0, stream>>>(esrc, edst, ew, h, out);
    }
}